// Round 5
// baseline (424.702 us; speedup 1.0000x reference)
//
#include <hip/hip_runtime.h>
#include <stdint.h>

typedef float f32x4 __attribute__((ext_vector_type(4)));
typedef __bf16 bf16x8 __attribute__((ext_vector_type(8)));
typedef unsigned short us4 __attribute__((ext_vector_type(4)));

__device__ __forceinline__ unsigned short f32_to_bf16(float f) {
  union { float f; uint32_t u; } v; v.f = f;
  return (unsigned short)((v.u + 0x7FFFu + ((v.u >> 16) & 1u)) >> 16);
}

__device__ __forceinline__ void gload16(const void* g, void* l) {
  __builtin_amdgcn_global_load_lds((const __attribute__((address_space(1))) void*)g,
                                   (__attribute__((address_space(3))) void*)l, 16, 0, 0);
}

// ---------------------------------------------------------------------------
// bf16 GEMM: C[M x N] = A[M x K] * Bt^T (Bt: NB x K). 128x128 tile, BK=32,
// 4 waves (64x64 each), DOUBLE-BUFFERED LDS (2 x 16KB): per step, stage tile
// t+1 into buf^1, compute tile t from buf, ONE barrier (its vmcnt(0) drain
// sits after the ds_read+MFMA window instead of immediately after issue).
// LDS per buf: A[k8][row][8] chunk-linear (4096 us) + B same (+4096).
// EPI: 0 = f32 partials (split-K) | 1 = relu(+bias)->bf16 | 2 = +bias->f32, col<NV
// ---------------------------------------------------------------------------
template <int EPI>
__global__ __launch_bounds__(256, 2) void gemm_bf16(
    const unsigned short* __restrict__ A, const unsigned short* __restrict__ Bt,
    int M, int NB, int K, int Mtiles, int Ntiles, int splits,
    float* __restrict__ outF, unsigned short* __restrict__ outH,
    const float* __restrict__ bias, const float* __restrict__ bias2,
    int NV, size_t splitStride)
{
  __shared__ unsigned short lds[16384];  // 2 bufs x (A 4096 | B 4096) ushorts
  const int tid = threadIdx.x;
  const int lane = tid & 63;
  const int wave = tid >> 6;

  int bid = blockIdx.x;
  const int mt = bid % Mtiles; bid /= Mtiles;
  const int nt = bid % Ntiles; bid /= Ntiles;
  const int sp = bid;

  const int nK = K >> 5;
  const int chunk = nK / splits;
  const int kBegin = sp * chunk;
  const int kEnd = kBegin + chunk;

  // staging: thread t loads chunks t and t+256 of A and of B (chunk = 16B).
  const int rowl = tid & 127;
  const int k8l = tid >> 7;
  int aRow = mt * 128 + rowl; if (aRow > M - 1) aRow = M - 1;
  int bRow = nt * 128 + rowl; if (bRow > NB - 1) bRow = NB - 1;
  const unsigned short* gA = A + (size_t)aRow * K + k8l * 8;
  const unsigned short* gB = Bt + (size_t)bRow * K + k8l * 8;

  // fragment read offsets (ushort units, within one buffer)
  const int k8 = lane >> 4;
  const int rsel = lane & 15;
  const int wrBase = (wave >> 1) * 64;
  const int wcBase = (wave & 1) * 64;
  int aOff[4], bOff[4];
#pragma unroll
  for (int m = 0; m < 4; ++m) aOff[m] = (k8 * 128 + wrBase + m * 16 + rsel) * 8;
#pragma unroll
  for (int n = 0; n < 4; ++n) bOff[n] = 4096 + (k8 * 128 + wcBase + n * 16 + rsel) * 8;

  f32x4 acc[4][4];
  const f32x4 zero = {0.f, 0.f, 0.f, 0.f};
#pragma unroll
  for (int m = 0; m < 4; ++m)
#pragma unroll
    for (int n = 0; n < 4; ++n) acc[m][n] = zero;

  auto stage = [&](int kt, int b) {
    const unsigned short* a = gA + kt * 32;
    const unsigned short* bsrc = gB + kt * 32;
    unsigned short* base = &lds[b * 8192];
    gload16(a,         base + tid * 8);
    gload16(a + 16,    base + (tid + 256) * 8);
    gload16(bsrc,      base + 4096 + tid * 8);
    gload16(bsrc + 16, base + 4096 + (tid + 256) * 8);
  };

  stage(kBegin, 0);
  __syncthreads();  // drains vmcnt(0) (compiler-inserted before s_barrier)
  int cur = 0;
  for (int kt = kBegin; kt < kEnd; ++kt) {
    if (kt + 1 < kEnd) stage(kt + 1, cur ^ 1);  // prefetch overlaps compute below
    const int cbase = cur * 8192;
    bf16x8 af[4], bfv[4];
#pragma unroll
    for (int m = 0; m < 4; ++m) af[m] = *(const bf16x8*)&lds[cbase + aOff[m]];
#pragma unroll
    for (int n = 0; n < 4; ++n) bfv[n] = *(const bf16x8*)&lds[cbase + bOff[n]];
#pragma unroll
    for (int m = 0; m < 4; ++m)
#pragma unroll
      for (int n = 0; n < 4; ++n)
        acc[m][n] = __builtin_amdgcn_mfma_f32_16x16x32_bf16(af[m], bfv[n], acc[m][n], 0, 0, 0);
    __syncthreads();  // prefetch drained; safe to overwrite cur next iter
    cur ^= 1;
  }

  // epilogue: C/D layout col = lane&15, row = (lane>>4)*4 + reg
  const int colBase = nt * 128 + wcBase + rsel;
  const int rowBase = mt * 128 + wrBase + (lane >> 4) * 4;
#pragma unroll
  for (int m = 0; m < 4; ++m) {
#pragma unroll
    for (int n = 0; n < 4; ++n) {
      const int col = colBase + n * 16;
#pragma unroll
      for (int j = 0; j < 4; ++j) {
        const int row = rowBase + m * 16 + j;
        if (row < M) {
          float v = acc[m][n][j];
          if (EPI == 0) {
            outF[sp * splitStride + (size_t)row * 1024 + col] = v;
          } else if (EPI == 1) {
            v += bias[col];
            v = fmaxf(v, 0.f);
            outH[(size_t)row * 1024 + col] = f32_to_bf16(v);
          } else {
            if (col < NV) {
              v += (col < 81) ? bias[col] : bias2[col - 81];
              outF[(size_t)row * NV + col] = v;
            }
          }
        }
      }
    }
  }
}

// f32 (R x C) -> bf16 transposed (C rows x R cols, ld=dstLd), dst rows += dstRowOff.
// 64x64 tile, 256 threads; vectorized f32x4 loads (when C%4==0) and us4 stores.
// Requires R % 64 == 0 (true for all weights here).
__global__ void transpose_to_bf16(const float* __restrict__ src, unsigned short* __restrict__ dst,
                                  int R, int C, int dstRowOff, int dstLd) {
  __shared__ unsigned short tile[64][66];  // LD=66: phase-2 reads ~2-way only
  const int c0 = blockIdx.x * 64, r0 = blockIdx.y * 64;
  const int t = threadIdx.x;
  const bool fast = ((C & 3) == 0) && (c0 + 64 <= C);
  const int lr0 = t >> 4;          // 0..15
  const int lc4 = (t & 15) * 4;    // 0..60
#pragma unroll
  for (int i = 0; i < 4; ++i) {
    const int lr = lr0 + i * 16;
    const size_t rowOff = (size_t)(r0 + lr) * C;
    if (fast) {
      f32x4 v = *(const f32x4*)(src + rowOff + c0 + lc4);
#pragma unroll
      for (int j = 0; j < 4; ++j) tile[lr][lc4 + j] = f32_to_bf16(v[j]);
    } else {
#pragma unroll
      for (int j = 0; j < 4; ++j) {
        const int c = c0 + lc4 + j;
        tile[lr][lc4 + j] = (c < C) ? f32_to_bf16(src[rowOff + c]) : (unsigned short)0;
      }
    }
  }
  __syncthreads();
  const int kk = (t & 15) * 4;  // dst-col chunk (src rows), 8B-aligned
#pragma unroll
  for (int i = 0; i < 4; ++i) {
    const int lc = lr0 + i * 16;
    const int c = c0 + lc;
    if (c < C) {
      us4 h;
#pragma unroll
      for (int j = 0; j < 4; ++j) h[j] = tile[kk + j][lc];
      *(us4*)(dst + (size_t)(dstRowOff + c) * dstLd + r0 + kk) = h;
    }
  }
}

__global__ void convert_to_bf16(const float* __restrict__ src, unsigned short* __restrict__ dst,
                                long n4) {
  for (long i = blockIdx.x * (long)blockDim.x + threadIdx.x; i < n4;
       i += (long)gridDim.x * blockDim.x) {
    f32x4 v = *(const f32x4*)(src + i * 4);
    us4 h;
#pragma unroll
    for (int j = 0; j < 4; ++j) h[j] = f32_to_bf16(v[j]);
    *(us4*)(dst + i * 4) = h;
  }
}

// sum split-K partials + bias + relu; write f32 to out cols [400,1424) and bf16 f6b
__global__ void reduce_bias_relu(const float* __restrict__ Cp, int splits, size_t sstride,
                                 const float* __restrict__ b6, float* __restrict__ out,
                                 unsigned short* __restrict__ f6b, int M) {
  const long total = (long)M * 256;
  for (long i = blockIdx.x * (long)blockDim.x + threadIdx.x; i < total;
       i += (long)gridDim.x * blockDim.x) {
    const long row = i >> 8;
    const int c4 = (int)(i & 255) * 4;
    const size_t off = ((size_t)row << 10) + c4;
    f32x4 s = *(const f32x4*)(Cp + off);
    for (int sp = 1; sp < splits; ++sp) s += *(const f32x4*)(Cp + (size_t)sp * sstride + off);
    s += *(const f32x4*)(b6 + c4);
    us4 h;
#pragma unroll
    for (int j = 0; j < 4; ++j) { s[j] = fmaxf(s[j], 0.f); h[j] = f32_to_bf16(s[j]); }
    *(f32x4*)(out + (size_t)row * 1424 + 400 + c4) = s;
    *(us4*)(f6b + off) = h;
  }
}

// per-row (one wave64 per row): softmax(81), decode, threshold-mask, write cols [0,400)
__global__ void head_epilogue(const float* __restrict__ cb, const float* __restrict__ boxes,
                              float* __restrict__ out, int M) {
  const float CLIP = 4.135166556742356f;  // log(1000/16)
  const int row = blockIdx.x * 4 + (threadIdx.x >> 6);
  const int lane = threadIdx.x & 63;
  if (row >= M) return;
  const float* L = cb + (size_t)row * 405;  // [logits(81) | reg(324)]
  const float v0 = L[lane];
  const float v1 = (lane < 17) ? L[64 + lane] : -1e30f;
  float mx = fmaxf(v0, v1);
#pragma unroll
  for (int off = 32; off; off >>= 1) mx = fmaxf(mx, __shfl_xor(mx, off, 64));
  float e0 = __expf(v0 - mx);
  float e1 = (lane < 17) ? __expf(v1 - mx) : 0.f;
  float sum = e0 + e1;
#pragma unroll
  for (int off = 32; off; off >>= 1) sum += __shfl_xor(sum, off, 64);
  const float inv = 1.f / sum;

  const float bx0 = boxes[row * 4 + 0], by0 = boxes[row * 4 + 1];
  const float bx1 = boxes[row * 4 + 2], by1 = boxes[row * 4 + 3];
  const float w = bx1 - bx0 + 1.f, h = by1 - by0 + 1.f;
  const float cx = bx0 + 0.5f * w, cy = by0 + 0.5f * h;
  float* orow = out + (size_t)row * 1424;

#pragma unroll
  for (int t = 0; t < 2; ++t) {
    const int c = (t == 0) ? lane : 64 + lane;
    const bool valid = (t == 0) ? (lane >= 1) : (lane < 17);
    if (valid) {
      const float p = ((t == 0) ? e0 : e1) * inv;
      const float* rg = L + 81 + c * 4;
      const float dx = rg[0] * 0.1f, dy = rg[1] * 0.1f;
      const float dw = fminf(rg[2] * 0.2f, CLIP), dh = fminf(rg[3] * 0.2f, CLIP);
      const float pcx = dx * w + cx, pcy = dy * h + cy;
      const float pw = __expf(dw) * w, ph = __expf(dh) * h;
      const bool keep = p > 0.05f;
      orow[c - 1] = keep ? p : 0.f;
      float* ob = orow + 80 + (c - 1) * 4;
      ob[0] = keep ? (pcx - 0.5f * pw) : 0.f;
      ob[1] = keep ? (pcy - 0.5f * ph) : 0.f;
      ob[2] = keep ? (pcx + 0.5f * pw - 1.f) : 0.f;
      ob[3] = keep ? (pcy + 0.5f * ph - 1.f) : 0.f;
    }
  }
}

extern "C" void kernel_launch(void* const* d_in, const int* in_sizes, int n_in,
                              void* d_out, int out_size, void* d_ws, size_t ws_size,
                              hipStream_t stream) {
  const float* x     = (const float*)d_in[0];  // 2000 x 256 x 7 x 7
  const float* boxes = (const float*)d_in[1];  // 2000 x 4
  const float* W6    = (const float*)d_in[2];  // 12544 x 1024
  const float* b6    = (const float*)d_in[3];
  const float* W7    = (const float*)d_in[4];  // 1024 x 1024
  const float* b7    = (const float*)d_in[5];
  const float* Wcls  = (const float*)d_in[6];  // 1024 x 81
  const float* bcls  = (const float*)d_in[7];
  const float* Wbox  = (const float*)d_in[8];  // 1024 x 324
  const float* bboxb = (const float*)d_in[9];
  float* out = (float*)d_out;

  const int M = 2000, D = 12544, H = 1024;
  char* p = (char*)d_ws;
  auto carve = [&](size_t bytes) { char* r = p; p += (bytes + 255) & ~(size_t)255; return r; };
  unsigned short* xb   = (unsigned short*)carve((size_t)M * D * 2);    // 50.2 MB
  unsigned short* W6T  = (unsigned short*)carve((size_t)H * D * 2);    // 25.7 MB
  unsigned short* W7T  = (unsigned short*)carve((size_t)H * H * 2);    //  2.1 MB
  unsigned short* WcbT = (unsigned short*)carve((size_t)405 * H * 2);  //  0.8 MB
  unsigned short* f6b  = (unsigned short*)carve((size_t)M * H * 2);    //  4.1 MB
  unsigned short* f7b  = (unsigned short*)carve((size_t)M * H * 2);    //  4.1 MB
  float* cbv           = (float*)carve((size_t)M * 405 * 4);           //  3.2 MB
  size_t used = (size_t)(p - (char*)d_ws);
  int splits = 8;  // 392 K-steps: /8 = 49 each; degrade if ws too small
  while (splits > 1 && used + (size_t)splits * M * H * 4 + 1024 > ws_size) splits >>= 1;
  float* Cp = (float*)carve((size_t)splits * M * H * 4);               // 65.5 MB @8

  // dtype prep
  convert_to_bf16<<<4096, 256, 0, stream>>>(x, xb, (long)M * D / 4);
  transpose_to_bf16<<<dim3(16, 196), 256, 0, stream>>>(W6, W6T, D, H, 0, D);
  transpose_to_bf16<<<dim3(16, 16), 256, 0, stream>>>(W7, W7T, H, H, 0, H);
  transpose_to_bf16<<<dim3(2, 16), 256, 0, stream>>>(Wcls, WcbT, H, 81, 0, H);
  transpose_to_bf16<<<dim3(6, 16), 256, 0, stream>>>(Wbox, WcbT, H, 324, 81, H);

  // f6 = relu(x @ W6 + b6): split-K MFMA GEMM + reduce
  gemm_bf16<0><<<16 * 8 * splits, 256, 0, stream>>>(xb, W6T, M, H, D, 16, 8, splits,
                                                    Cp, nullptr, nullptr, nullptr, 0,
                                                    (size_t)M * H);
  reduce_bias_relu<<<2048, 256, 0, stream>>>(Cp, splits, (size_t)M * H, b6, out, f6b, M);

  // f7 = relu(f6 @ W7 + b7)
  gemm_bf16<1><<<16 * 8, 256, 0, stream>>>(f6b, W7T, M, H, H, 16, 8, 1,
                                           nullptr, f7b, b7, nullptr, 0, 0);

  // [logits | reg] = f7 @ [Wcls | Wbox] + [bcls | bbox_b]   (N=405 -> 4 tiles)
  gemm_bf16<2><<<16 * 4, 256, 0, stream>>>(f7b, WcbT, M, 405, H, 16, 4, 1,
                                           cbv, nullptr, bcls, bboxb, 405, 0);

  // softmax + decode + mask -> out cols [0,400)
  head_epilogue<<<(M + 3) / 4, 256, 0, stream>>>(cbv, boxes, out, M);
}

// Round 6
// 407.277 us; speedup vs baseline: 1.0428x; 1.0428x over previous
//
#include <hip/hip_runtime.h>
#include <stdint.h>

typedef float f32x4 __attribute__((ext_vector_type(4)));
typedef __bf16 bf16x8 __attribute__((ext_vector_type(8)));
typedef unsigned short us4 __attribute__((ext_vector_type(4)));

__device__ __forceinline__ unsigned short f32_to_bf16(float f) {
  union { float f; uint32_t u; } v; v.f = f;
  return (unsigned short)((v.u + 0x7FFFu + ((v.u >> 16) & 1u)) >> 16);
}

__device__ __forceinline__ void gload16(const void* g, void* l) {
  __builtin_amdgcn_global_load_lds((const __attribute__((address_space(1))) void*)g,
                                   (__attribute__((address_space(3))) void*)l, 16, 0, 0);
}

// ---------------------------------------------------------------------------
// bf16 GEMM: C[M x N] = A[M x K] * Bt^T (Bt: NB x K). 128x128 tile, BK=32,
// 4 waves (64x64 each), double-buffered LDS, ONE barrier per K-step.
// Block mapping: bijective XCD swizzle (grid%8==0 required): xcd = bid&7 gets
// contiguous wg chunk; decode nt FASTEST, sp SLOWEST. For GEMM1 (splits=8)
// each XCD owns exactly one K-split: B-slice (3.2MB) L2-resident, A-slice
// streamed once; 8 consecutive co-XCD blocks share one A-panel.
// EPI: 0 = f32 partials (split-K) | 1 = relu(+bias)->bf16 | 2 = +bias->f32, col<NV
// ---------------------------------------------------------------------------
template <int EPI>
__global__ __launch_bounds__(256, 2) void gemm_bf16(
    const unsigned short* __restrict__ A, const unsigned short* __restrict__ Bt,
    int M, int NB, int K, int Mtiles, int Ntiles, int splits,
    float* __restrict__ outF, unsigned short* __restrict__ outH,
    const float* __restrict__ bias, const float* __restrict__ bias2,
    int NV, size_t splitStride)
{
  __shared__ unsigned short lds[16384];  // 2 bufs x (A 4096 | B 4096) ushorts
  const int tid = threadIdx.x;
  const int lane = tid & 63;
  const int wave = tid >> 6;

  // XCD-aware bijective swizzle (nwg % 8 == 0 guaranteed by launcher)
  const int nwg = Mtiles * Ntiles * splits;
  const int per = nwg >> 3;
  int wg = (blockIdx.x & 7) * per + (blockIdx.x >> 3);
  const int nt = wg % Ntiles; wg /= Ntiles;
  const int mt = wg % Mtiles; wg /= Mtiles;
  const int sp = wg;

  const int nK = K >> 5;
  const int chunk = nK / splits;
  const int kBegin = sp * chunk;
  const int kEnd = kBegin + chunk;

  // staging: thread t loads 16B chunks t and t+256 of A and of B.
  const int rowl = tid & 127;
  const int k8l = tid >> 7;
  int aRow = mt * 128 + rowl; if (aRow > M - 1) aRow = M - 1;
  int bRow = nt * 128 + rowl; if (bRow > NB - 1) bRow = NB - 1;
  const unsigned short* gA = A + (size_t)aRow * K + k8l * 8;
  const unsigned short* gB = Bt + (size_t)bRow * K + k8l * 8;

  // fragment read offsets (ushort units, within one buffer)
  const int k8 = lane >> 4;
  const int rsel = lane & 15;
  const int wrBase = (wave >> 1) * 64;
  const int wcBase = (wave & 1) * 64;
  int aOff[4], bOff[4];
#pragma unroll
  for (int m = 0; m < 4; ++m) aOff[m] = (k8 * 128 + wrBase + m * 16 + rsel) * 8;
#pragma unroll
  for (int n = 0; n < 4; ++n) bOff[n] = 4096 + (k8 * 128 + wcBase + n * 16 + rsel) * 8;

  f32x4 acc[4][4];
  const f32x4 zero = {0.f, 0.f, 0.f, 0.f};
#pragma unroll
  for (int m = 0; m < 4; ++m)
#pragma unroll
    for (int n = 0; n < 4; ++n) acc[m][n] = zero;

  auto stage = [&](int kt, int b) {
    const unsigned short* a = gA + kt * 32;
    const unsigned short* bsrc = gB + kt * 32;
    unsigned short* base = &lds[b * 8192];
    gload16(a,         base + tid * 8);
    gload16(a + 16,    base + (tid + 256) * 8);
    gload16(bsrc,      base + 4096 + tid * 8);
    gload16(bsrc + 16, base + 4096 + (tid + 256) * 8);
  };

  stage(kBegin, 0);
  __syncthreads();  // drains vmcnt(0) (compiler-inserted before s_barrier)
  int cur = 0;
  for (int kt = kBegin; kt < kEnd; ++kt) {
    if (kt + 1 < kEnd) stage(kt + 1, cur ^ 1);  // prefetch overlaps compute below
    const int cbase = cur * 8192;
    bf16x8 af[4], bfv[4];
#pragma unroll
    for (int m = 0; m < 4; ++m) af[m] = *(const bf16x8*)&lds[cbase + aOff[m]];
#pragma unroll
    for (int n = 0; n < 4; ++n) bfv[n] = *(const bf16x8*)&lds[cbase + bOff[n]];
#pragma unroll
    for (int m = 0; m < 4; ++m)
#pragma unroll
      for (int n = 0; n < 4; ++n)
        acc[m][n] = __builtin_amdgcn_mfma_f32_16x16x32_bf16(af[m], bfv[n], acc[m][n], 0, 0, 0);
    __syncthreads();  // prefetch drained; safe to overwrite cur next iter
    cur ^= 1;
  }

  // epilogue: C/D layout col = lane&15, row = (lane>>4)*4 + reg
  const int colBase = nt * 128 + wcBase + rsel;
  const int rowBase = mt * 128 + wrBase + (lane >> 4) * 4;
#pragma unroll
  for (int m = 0; m < 4; ++m) {
#pragma unroll
    for (int n = 0; n < 4; ++n) {
      const int col = colBase + n * 16;
#pragma unroll
      for (int j = 0; j < 4; ++j) {
        const int row = rowBase + m * 16 + j;
        if (row < M) {
          float v = acc[m][n][j];
          if (EPI == 0) {
            outF[sp * splitStride + (size_t)row * 1024 + col] = v;
          } else if (EPI == 1) {
            v += bias[col];
            v = fmaxf(v, 0.f);
            outH[(size_t)row * 1024 + col] = f32_to_bf16(v);
          } else {
            if (col < NV) {
              v += (col < 81) ? bias[col] : bias2[col - 81];
              outF[(size_t)row * NV + col] = v;
            }
          }
        }
      }
    }
  }
}

// f32 (R x C) -> bf16 transposed (C rows x R cols, ld=dstLd), dst rows += dstRowOff.
// 64x64 tile, 256 threads; vectorized f32x4 loads (when possible) and us4 stores.
// Requires R % 64 == 0 (true for all weights here).
__global__ void transpose_to_bf16(const float* __restrict__ src, unsigned short* __restrict__ dst,
                                  int R, int C, int dstRowOff, int dstLd) {
  __shared__ unsigned short tile[64][66];
  const int c0 = blockIdx.x * 64, r0 = blockIdx.y * 64;
  const int t = threadIdx.x;
  const bool fast = ((C & 3) == 0) && (c0 + 64 <= C);
  const int lr0 = t >> 4;          // 0..15
  const int lc4 = (t & 15) * 4;    // 0..60
#pragma unroll
  for (int i = 0; i < 4; ++i) {
    const int lr = lr0 + i * 16;
    const size_t rowOff = (size_t)(r0 + lr) * C;
    if (fast) {
      f32x4 v = *(const f32x4*)(src + rowOff + c0 + lc4);
#pragma unroll
      for (int j = 0; j < 4; ++j) tile[lr][lc4 + j] = f32_to_bf16(v[j]);
    } else {
#pragma unroll
      for (int j = 0; j < 4; ++j) {
        const int c = c0 + lc4 + j;
        tile[lr][lc4 + j] = (c < C) ? f32_to_bf16(src[rowOff + c]) : (unsigned short)0;
      }
    }
  }
  __syncthreads();
  const int kk = (t & 15) * 4;  // dst-col chunk (src rows), 8B-aligned
#pragma unroll
  for (int i = 0; i < 4; ++i) {
    const int lc = lr0 + i * 16;
    const int c = c0 + lc;
    if (c < C) {
      us4 h;
#pragma unroll
      for (int j = 0; j < 4; ++j) h[j] = tile[kk + j][lc];
      *(us4*)(dst + (size_t)(dstRowOff + c) * dstLd + r0 + kk) = h;
    }
  }
}

__global__ void convert_to_bf16(const float* __restrict__ src, unsigned short* __restrict__ dst,
                                long n4) {
  for (long i = blockIdx.x * (long)blockDim.x + threadIdx.x; i < n4;
       i += (long)gridDim.x * blockDim.x) {
    f32x4 v = *(const f32x4*)(src + i * 4);
    us4 h;
#pragma unroll
    for (int j = 0; j < 4; ++j) h[j] = f32_to_bf16(v[j]);
    *(us4*)(dst + i * 4) = h;
  }
}

// sum split-K partials (+bias, relu); optionally write f32 rows into out cols
// [400,1424) (GEMM1 path, outF32 != null) and always write bf16 to outBf.
__global__ void reduce_bias_act(const float* __restrict__ Cp, int splits, size_t sstride,
                                const float* __restrict__ bias, float* __restrict__ outF32,
                                unsigned short* __restrict__ outBf, int M) {
  const long total = (long)M * 256;
  for (long i = blockIdx.x * (long)blockDim.x + threadIdx.x; i < total;
       i += (long)gridDim.x * blockDim.x) {
    const long row = i >> 8;
    const int c4 = (int)(i & 255) * 4;
    const size_t off = ((size_t)row << 10) + c4;
    f32x4 s = *(const f32x4*)(Cp + off);
    for (int sp = 1; sp < splits; ++sp) s += *(const f32x4*)(Cp + (size_t)sp * sstride + off);
    s += *(const f32x4*)(bias + c4);
    us4 h;
#pragma unroll
    for (int j = 0; j < 4; ++j) { s[j] = fmaxf(s[j], 0.f); h[j] = f32_to_bf16(s[j]); }
    if (outF32) *(f32x4*)(outF32 + (size_t)row * 1424 + 400 + c4) = s;
    *(us4*)(outBf + off) = h;
  }
}

// per-row (one wave64 per row): softmax(81), decode, threshold-mask, write cols [0,400)
__global__ void head_epilogue(const float* __restrict__ cb, const float* __restrict__ boxes,
                              float* __restrict__ out, int M) {
  const float CLIP = 4.135166556742356f;  // log(1000/16)
  const int row = blockIdx.x * 4 + (threadIdx.x >> 6);
  const int lane = threadIdx.x & 63;
  if (row >= M) return;
  const float* L = cb + (size_t)row * 405;  // [logits(81) | reg(324)]
  const float v0 = L[lane];
  const float v1 = (lane < 17) ? L[64 + lane] : -1e30f;
  float mx = fmaxf(v0, v1);
#pragma unroll
  for (int off = 32; off; off >>= 1) mx = fmaxf(mx, __shfl_xor(mx, off, 64));
  float e0 = __expf(v0 - mx);
  float e1 = (lane < 17) ? __expf(v1 - mx) : 0.f;
  float sum = e0 + e1;
#pragma unroll
  for (int off = 32; off; off >>= 1) sum += __shfl_xor(sum, off, 64);
  const float inv = 1.f / sum;

  const float bx0 = boxes[row * 4 + 0], by0 = boxes[row * 4 + 1];
  const float bx1 = boxes[row * 4 + 2], by1 = boxes[row * 4 + 3];
  const float w = bx1 - bx0 + 1.f, h = by1 - by0 + 1.f;
  const float cx = bx0 + 0.5f * w, cy = by0 + 0.5f * h;
  float* orow = out + (size_t)row * 1424;

#pragma unroll
  for (int t = 0; t < 2; ++t) {
    const int c = (t == 0) ? lane : 64 + lane;
    const bool valid = (t == 0) ? (lane >= 1) : (lane < 17);
    if (valid) {
      const float p = ((t == 0) ? e0 : e1) * inv;
      const float* rg = L + 81 + c * 4;
      const float dx = rg[0] * 0.1f, dy = rg[1] * 0.1f;
      const float dw = fminf(rg[2] * 0.2f, CLIP), dh = fminf(rg[3] * 0.2f, CLIP);
      const float pcx = dx * w + cx, pcy = dy * h + cy;
      const float pw = __expf(dw) * w, ph = __expf(dh) * h;
      const bool keep = p > 0.05f;
      orow[c - 1] = keep ? p : 0.f;
      float* ob = orow + 80 + (c - 1) * 4;
      ob[0] = keep ? (pcx - 0.5f * pw) : 0.f;
      ob[1] = keep ? (pcy - 0.5f * ph) : 0.f;
      ob[2] = keep ? (pcx + 0.5f * pw - 1.f) : 0.f;
      ob[3] = keep ? (pcy + 0.5f * ph - 1.f) : 0.f;
    }
  }
}

extern "C" void kernel_launch(void* const* d_in, const int* in_sizes, int n_in,
                              void* d_out, int out_size, void* d_ws, size_t ws_size,
                              hipStream_t stream) {
  const float* x     = (const float*)d_in[0];  // 2000 x 256 x 7 x 7
  const float* boxes = (const float*)d_in[1];  // 2000 x 4
  const float* W6    = (const float*)d_in[2];  // 12544 x 1024
  const float* b6    = (const float*)d_in[3];
  const float* W7    = (const float*)d_in[4];  // 1024 x 1024
  const float* b7    = (const float*)d_in[5];
  const float* Wcls  = (const float*)d_in[6];  // 1024 x 81
  const float* bcls  = (const float*)d_in[7];
  const float* Wbox  = (const float*)d_in[8];  // 1024 x 324
  const float* bboxb = (const float*)d_in[9];
  float* out = (float*)d_out;

  const int M = 2000, D = 12544, H = 1024;
  char* p = (char*)d_ws;
  auto carve = [&](size_t bytes) { char* r = p; p += (bytes + 255) & ~(size_t)255; return r; };
  unsigned short* xb   = (unsigned short*)carve((size_t)M * D * 2);    // 50.2 MB
  unsigned short* W6T  = (unsigned short*)carve((size_t)H * D * 2);    // 25.7 MB
  unsigned short* W7T  = (unsigned short*)carve((size_t)H * H * 2);    //  2.1 MB
  unsigned short* WcbT = (unsigned short*)carve((size_t)405 * H * 2);  //  0.8 MB
  unsigned short* f6b  = (unsigned short*)carve((size_t)M * H * 2);    //  4.1 MB
  unsigned short* f7b  = (unsigned short*)carve((size_t)M * H * 2);    //  4.1 MB
  float* cbv           = (float*)carve((size_t)M * 405 * 4);           //  3.2 MB
  size_t used = (size_t)(p - (char*)d_ws);
  int splits = 8;  // 392 K-steps: /8 = 49 each; one split per XCD; degrade if ws small
  while (splits > 1 && used + (size_t)splits * M * H * 4 + 1024 > ws_size) splits >>= 1;
  float* Cp = (float*)carve((size_t)splits * M * H * 4);               // 65.5 MB @8

  // dtype prep
  convert_to_bf16<<<4096, 256, 0, stream>>>(x, xb, (long)M * D / 4);
  transpose_to_bf16<<<dim3(16, 196), 256, 0, stream>>>(W6, W6T, D, H, 0, D);
  transpose_to_bf16<<<dim3(16, 16), 256, 0, stream>>>(W7, W7T, H, H, 0, H);
  transpose_to_bf16<<<dim3(2, 16), 256, 0, stream>>>(Wcls, WcbT, H, 81, 0, H);
  transpose_to_bf16<<<dim3(6, 16), 256, 0, stream>>>(Wbox, WcbT, H, 324, 81, H);

  // f6 = relu(x @ W6 + b6): split-K MFMA GEMM + reduce
  gemm_bf16<0><<<16 * 8 * splits, 256, 0, stream>>>(xb, W6T, M, H, D, 16, 8, splits,
                                                    Cp, nullptr, nullptr, nullptr, 0,
                                                    (size_t)M * H);
  reduce_bias_act<<<2048, 256, 0, stream>>>(Cp, splits, (size_t)M * H, b6, out, f6b, M);

  // f7 = relu(f6 @ W7 + b7): split-K 2 (reuses Cp space, free after reduce above)
  const int splits2 = (splits >= 2) ? 2 : 1;
  if (splits2 == 2) {
    gemm_bf16<0><<<16 * 8 * 2, 256, 0, stream>>>(f6b, W7T, M, H, H, 16, 8, 2,
                                                 Cp, nullptr, nullptr, nullptr, 0,
                                                 (size_t)M * H);
    reduce_bias_act<<<2048, 256, 0, stream>>>(Cp, 2, (size_t)M * H, b7, nullptr, f7b, M);
  } else {
    gemm_bf16<1><<<16 * 8, 256, 0, stream>>>(f6b, W7T, M, H, H, 16, 8, 1,
                                             nullptr, f7b, b7, nullptr, 0, 0);
  }

  // [logits | reg] = f7 @ [Wcls | Wbox] + [bcls | bbox_b]   (N=405 -> 4 tiles)
  gemm_bf16<2><<<16 * 4, 256, 0, stream>>>(f7b, WcbT, M, 405, H, 16, 4, 1,
                                           cbv, nullptr, bcls, bboxb, 405, 0);

  // softmax + decode + mask -> out cols [0,400)
  head_epilogue<<<(M + 3) / 4, 256, 0, stream>>>(cbv, boxes, out, M);
}

// Round 7
// 405.396 us; speedup vs baseline: 1.0476x; 1.0046x over previous
//
#include <hip/hip_runtime.h>
#include <stdint.h>

typedef float f32x4 __attribute__((ext_vector_type(4)));
typedef __bf16 bf16x8 __attribute__((ext_vector_type(8)));
typedef unsigned short us4 __attribute__((ext_vector_type(4)));

__device__ __forceinline__ unsigned short f32_to_bf16(float f) {
  union { float f; uint32_t u; } v; v.f = f;
  return (unsigned short)((v.u + 0x7FFFu + ((v.u >> 16) & 1u)) >> 16);
}

__device__ __forceinline__ void gload16(const void* g, void* l) {
  __builtin_amdgcn_global_load_lds((const __attribute__((address_space(1))) void*)g,
                                   (__attribute__((address_space(3))) void*)l, 16, 0, 0);
}

// ---------------------------------------------------------------------------
// bf16 GEMM: C[M x N] = A[M x K] * Bt^T (Bt: NB x K). 128x128 tile, BK=64,
// 4 waves (64x64 each), double-buffered LDS (2 x 32KB), ONE barrier per step.
// BK=64 amortizes the per-barrier vmcnt(0) latency drain over 2x the MFMA
// work vs BK=32 (R6: step time was pinned at load latency ~1450cyc).
// LDS per buf: A[k8 0..7][row 0..127][8] chunk-linear 16KB, B same +8192us.
// Block mapping: bijective XCD swizzle (grid%8==0), nt fastest, sp slowest.
// EPI: 0 = f32 partials (split-K) | 1 = relu(+bias)->bf16 | 2 = +bias->f32, col<NV
// Requires K % 64 == 0 and (K/64) % splits == 0.
// ---------------------------------------------------------------------------
template <int EPI>
__global__ __launch_bounds__(256, 2) void gemm_bf16(
    const unsigned short* __restrict__ A, const unsigned short* __restrict__ Bt,
    int M, int NB, int K, int Mtiles, int Ntiles, int splits,
    float* __restrict__ outF, unsigned short* __restrict__ outH,
    const float* __restrict__ bias, const float* __restrict__ bias2,
    int NV, size_t splitStride)
{
  __shared__ unsigned short lds[32768];  // 2 bufs x (A 8192 | B 8192) ushorts = 64KB
  const int tid = threadIdx.x;
  const int lane = tid & 63;
  const int wave = tid >> 6;

  // XCD-aware bijective swizzle (nwg % 8 == 0 guaranteed by launcher)
  const int nwg = Mtiles * Ntiles * splits;
  const int per = nwg >> 3;
  int wg = (blockIdx.x & 7) * per + (blockIdx.x >> 3);
  const int nt = wg % Ntiles; wg /= Ntiles;
  const int mt = wg % Mtiles; wg /= Mtiles;
  const int sp = wg;

  const int nK = K >> 6;  // BK=64 steps
  const int chunk = nK / splits;
  const int kBegin = sp * chunk;
  const int kEnd = kBegin + chunk;

  // staging: thread t loads 16B chunks t+j*256 (j=0..3) of A and of B.
  // chunk c -> (k8 = c>>7 in 0..7, row = c&127); same row for all j (k8 += 2j).
  const int rowl = tid & 127;
  const int k8l = tid >> 7;  // 0 or 1
  int aRow = mt * 128 + rowl; if (aRow > M - 1) aRow = M - 1;
  int bRow = nt * 128 + rowl; if (bRow > NB - 1) bRow = NB - 1;
  const unsigned short* gA = A + (size_t)aRow * K + k8l * 8;
  const unsigned short* gB = Bt + (size_t)bRow * K + k8l * 8;

  // fragment read offsets (ushort units, within one buffer), kk = K-half (0/1)
  const int k8f = lane >> 4;   // 0..3
  const int rsel = lane & 15;
  const int wrBase = (wave >> 1) * 64;
  const int wcBase = (wave & 1) * 64;
  int aOff[2][4], bOff[2][4];
#pragma unroll
  for (int kk = 0; kk < 2; ++kk) {
#pragma unroll
    for (int m = 0; m < 4; ++m)
      aOff[kk][m] = ((kk * 4 + k8f) * 128 + wrBase + m * 16 + rsel) * 8;
#pragma unroll
    for (int n = 0; n < 4; ++n)
      bOff[kk][n] = 8192 + ((kk * 4 + k8f) * 128 + wcBase + n * 16 + rsel) * 8;
  }

  f32x4 acc[4][4];
  const f32x4 zero = {0.f, 0.f, 0.f, 0.f};
#pragma unroll
  for (int m = 0; m < 4; ++m)
#pragma unroll
    for (int n = 0; n < 4; ++n) acc[m][n] = zero;

  auto stage = [&](int kt, int b) {
    const unsigned short* a = gA + (size_t)kt * 64;
    const unsigned short* bsrc = gB + (size_t)kt * 64;
    unsigned short* base = &lds[b * 16384];
#pragma unroll
    for (int j = 0; j < 4; ++j) {
      gload16(a + j * 16,    base + (tid + j * 256) * 8);
      gload16(bsrc + j * 16, base + 8192 + (tid + j * 256) * 8);
    }
  };

  stage(kBegin, 0);
  __syncthreads();  // compiler drains vmcnt(0) before s_barrier
  int cur = 0;
  for (int kt = kBegin; kt < kEnd; ++kt) {
    if (kt + 1 < kEnd) stage(kt + 1, cur ^ 1);  // prefetch overlaps compute below
    const int cb = cur * 16384;
#pragma unroll
    for (int kk = 0; kk < 2; ++kk) {
      bf16x8 af[4], bfv[4];
#pragma unroll
      for (int m = 0; m < 4; ++m) af[m] = *(const bf16x8*)&lds[cb + aOff[kk][m]];
#pragma unroll
      for (int n = 0; n < 4; ++n) bfv[n] = *(const bf16x8*)&lds[cb + bOff[kk][n]];
#pragma unroll
      for (int m = 0; m < 4; ++m)
#pragma unroll
        for (int n = 0; n < 4; ++n)
          acc[m][n] = __builtin_amdgcn_mfma_f32_16x16x32_bf16(af[m], bfv[n], acc[m][n], 0, 0, 0);
    }
    __syncthreads();  // prefetch drained; safe to overwrite cur next iter
    cur ^= 1;
  }

  // epilogue: C/D layout col = lane&15, row = (lane>>4)*4 + reg
  const int colBase = nt * 128 + wcBase + rsel;
  const int rowBase = mt * 128 + wrBase + (lane >> 4) * 4;
#pragma unroll
  for (int m = 0; m < 4; ++m) {
#pragma unroll
    for (int n = 0; n < 4; ++n) {
      const int col = colBase + n * 16;
#pragma unroll
      for (int j = 0; j < 4; ++j) {
        const int row = rowBase + m * 16 + j;
        if (row < M) {
          float v = acc[m][n][j];
          if (EPI == 0) {
            outF[sp * splitStride + (size_t)row * 1024 + col] = v;
          } else if (EPI == 1) {
            v += bias[col];
            v = fmaxf(v, 0.f);
            outH[(size_t)row * 1024 + col] = f32_to_bf16(v);
          } else {
            if (col < NV) {
              v += (col < 81) ? bias[col] : bias2[col - 81];
              outF[(size_t)row * NV + col] = v;
            }
          }
        }
      }
    }
  }
}

// 64x64 transpose tile: f32 (R x C) -> bf16 (C x R at dstLd), rows += dstRowOff.
__device__ __forceinline__ void transpose_tile(
    const float* __restrict__ src, unsigned short* __restrict__ dst,
    int R, int C, int dstRowOff, int dstLd, int bx, int by,
    unsigned short (*tile)[66]) {
  const int c0 = bx * 64, r0 = by * 64;
  const int t = threadIdx.x;
  const bool fast = ((C & 3) == 0) && (c0 + 64 <= C);
  const int lr0 = t >> 4;          // 0..15
  const int lc4 = (t & 15) * 4;    // 0..60
#pragma unroll
  for (int i = 0; i < 4; ++i) {
    const int lr = lr0 + i * 16;
    const size_t rowOff = (size_t)(r0 + lr) * C;
    if (fast) {
      f32x4 v = *(const f32x4*)(src + rowOff + c0 + lc4);
#pragma unroll
      for (int j = 0; j < 4; ++j) tile[lr][lc4 + j] = f32_to_bf16(v[j]);
    } else {
#pragma unroll
      for (int j = 0; j < 4; ++j) {
        const int c = c0 + lc4 + j;
        tile[lr][lc4 + j] = (c < C) ? f32_to_bf16(src[rowOff + c]) : (unsigned short)0;
      }
    }
  }
  __syncthreads();
  const int kk = (t & 15) * 4;  // dst-col chunk (src rows), 8B-aligned
#pragma unroll
  for (int i = 0; i < 4; ++i) {
    const int lc = lr0 + i * 16;
    const int c = c0 + lc;
    if (c < C) {
      us4 h;
#pragma unroll
      for (int j = 0; j < 4; ++j) h[j] = tile[kk + j][lc];
      *(us4*)(dst + (size_t)(dstRowOff + c) * dstLd + r0 + kk) = h;
    }
  }
}

// Fused prep: blocks [0,2048) convert x->bf16; then W6/W7/Wcls/Wbox transposes.
__global__ __launch_bounds__(256) void prep(
    const float* __restrict__ x, unsigned short* __restrict__ xb, long n4,
    const float* __restrict__ W6, unsigned short* __restrict__ W6T,
    const float* __restrict__ W7, unsigned short* __restrict__ W7T,
    const float* __restrict__ Wcls, const float* __restrict__ Wbox,
    unsigned short* __restrict__ WcbT) {
  __shared__ unsigned short tile[64][66];
  const int b = blockIdx.x;
  if (b < 2048) {
    for (long i = (long)b * 256 + threadIdx.x; i < n4; i += 2048L * 256) {
      f32x4 v = *(const f32x4*)(x + i * 4);
      us4 h;
#pragma unroll
      for (int j = 0; j < 4; ++j) h[j] = f32_to_bf16(v[j]);
      *(us4*)(xb + i * 4) = h;
    }
  } else if (b < 2048 + 3136) {       // W6: 12544 x 1024 -> 16 x 196 tiles
    const int i = b - 2048;
    transpose_tile(W6, W6T, 12544, 1024, 0, 12544, i & 15, i >> 4, tile);
  } else if (b < 2048 + 3136 + 256) { // W7: 1024 x 1024 -> 16 x 16
    const int i = b - (2048 + 3136);
    transpose_tile(W7, W7T, 1024, 1024, 0, 1024, i & 15, i >> 4, tile);
  } else if (b < 2048 + 3136 + 256 + 32) {  // Wcls: 1024 x 81 -> 2 x 16
    const int i = b - (2048 + 3136 + 256);
    transpose_tile(Wcls, WcbT, 1024, 81, 0, 1024, i & 1, i >> 1, tile);
  } else {                            // Wbox: 1024 x 324 -> 6 x 16
    const int i = b - (2048 + 3136 + 256 + 32);
    transpose_tile(Wbox, WcbT, 1024, 324, 81, 1024, i % 6, i / 6, tile);
  }
}

// sum split-K partials + bias + relu; write f32 rows to out cols [400,1424) and bf16 f6b
__global__ void reduce_bias_act(const float* __restrict__ Cp, int splits, size_t sstride,
                                const float* __restrict__ bias, float* __restrict__ outF32,
                                unsigned short* __restrict__ outBf, int M) {
  const long total = (long)M * 256;
  for (long i = blockIdx.x * (long)blockDim.x + threadIdx.x; i < total;
       i += (long)gridDim.x * blockDim.x) {
    const long row = i >> 8;
    const int c4 = (int)(i & 255) * 4;
    const size_t off = ((size_t)row << 10) + c4;
    f32x4 s = *(const f32x4*)(Cp + off);
    for (int sp = 1; sp < splits; ++sp) s += *(const f32x4*)(Cp + (size_t)sp * sstride + off);
    s += *(const f32x4*)(bias + c4);
    us4 h;
#pragma unroll
    for (int j = 0; j < 4; ++j) { s[j] = fmaxf(s[j], 0.f); h[j] = f32_to_bf16(s[j]); }
    if (outF32) *(f32x4*)(outF32 + (size_t)row * 1424 + 400 + c4) = s;
    *(us4*)(outBf + off) = h;
  }
}

// per-row (one wave64 per row): softmax(81), decode, threshold-mask, write cols [0,400)
__global__ void head_epilogue(const float* __restrict__ cb, const float* __restrict__ boxes,
                              float* __restrict__ out, int M) {
  const float CLIP = 4.135166556742356f;  // log(1000/16)
  const int row = blockIdx.x * 4 + (threadIdx.x >> 6);
  const int lane = threadIdx.x & 63;
  if (row >= M) return;
  const float* L = cb + (size_t)row * 405;  // [logits(81) | reg(324)]
  const float v0 = L[lane];
  const float v1 = (lane < 17) ? L[64 + lane] : -1e30f;
  float mx = fmaxf(v0, v1);
#pragma unroll
  for (int off = 32; off; off >>= 1) mx = fmaxf(mx, __shfl_xor(mx, off, 64));
  float e0 = __expf(v0 - mx);
  float e1 = (lane < 17) ? __expf(v1 - mx) : 0.f;
  float sum = e0 + e1;
#pragma unroll
  for (int off = 32; off; off >>= 1) sum += __shfl_xor(sum, off, 64);
  const float inv = 1.f / sum;

  const float bx0 = boxes[row * 4 + 0], by0 = boxes[row * 4 + 1];
  const float bx1 = boxes[row * 4 + 2], by1 = boxes[row * 4 + 3];
  const float w = bx1 - bx0 + 1.f, h = by1 - by0 + 1.f;
  const float cx = bx0 + 0.5f * w, cy = by0 + 0.5f * h;
  float* orow = out + (size_t)row * 1424;

#pragma unroll
  for (int t = 0; t < 2; ++t) {
    const int c = (t == 0) ? lane : 64 + lane;
    const bool valid = (t == 0) ? (lane >= 1) : (lane < 17);
    if (valid) {
      const float p = ((t == 0) ? e0 : e1) * inv;
      const float* rg = L + 81 + c * 4;
      const float dx = rg[0] * 0.1f, dy = rg[1] * 0.1f;
      const float dw = fminf(rg[2] * 0.2f, CLIP), dh = fminf(rg[3] * 0.2f, CLIP);
      const float pcx = dx * w + cx, pcy = dy * h + cy;
      const float pw = __expf(dw) * w, ph = __expf(dh) * h;
      const bool keep = p > 0.05f;
      orow[c - 1] = keep ? p : 0.f;
      float* ob = orow + 80 + (c - 1) * 4;
      ob[0] = keep ? (pcx - 0.5f * pw) : 0.f;
      ob[1] = keep ? (pcy - 0.5f * ph) : 0.f;
      ob[2] = keep ? (pcx + 0.5f * pw - 1.f) : 0.f;
      ob[3] = keep ? (pcy + 0.5f * ph - 1.f) : 0.f;
    }
  }
}

extern "C" void kernel_launch(void* const* d_in, const int* in_sizes, int n_in,
                              void* d_out, int out_size, void* d_ws, size_t ws_size,
                              hipStream_t stream) {
  const float* x     = (const float*)d_in[0];  // 2000 x 256 x 7 x 7
  const float* boxes = (const float*)d_in[1];  // 2000 x 4
  const float* W6    = (const float*)d_in[2];  // 12544 x 1024
  const float* b6    = (const float*)d_in[3];
  const float* W7    = (const float*)d_in[4];  // 1024 x 1024
  const float* b7    = (const float*)d_in[5];
  const float* Wcls  = (const float*)d_in[6];  // 1024 x 81
  const float* bcls  = (const float*)d_in[7];
  const float* Wbox  = (const float*)d_in[8];  // 1024 x 324
  const float* bboxb = (const float*)d_in[9];
  float* out = (float*)d_out;

  const int M = 2000, D = 12544, H = 1024;
  char* p = (char*)d_ws;
  auto carve = [&](size_t bytes) { char* r = p; p += (bytes + 255) & ~(size_t)255; return r; };
  unsigned short* xb   = (unsigned short*)carve((size_t)M * D * 2);    // 50.2 MB
  unsigned short* W6T  = (unsigned short*)carve((size_t)H * D * 2);    // 25.7 MB
  unsigned short* W7T  = (unsigned short*)carve((size_t)H * H * 2);    //  2.1 MB
  unsigned short* WcbT = (unsigned short*)carve((size_t)405 * H * 2);  //  0.8 MB
  unsigned short* f6b  = (unsigned short*)carve((size_t)M * H * 2);    //  4.1 MB
  unsigned short* f7b  = (unsigned short*)carve((size_t)M * H * 2);    //  4.1 MB
  float* cbv           = (float*)carve((size_t)M * 405 * 4);           //  3.2 MB
  size_t used = (size_t)(p - (char*)d_ws);
  int splits = 4;  // 196 BK64-steps: /4 = 49 each; degrade if ws too small
  while (splits > 1 && used + (size_t)splits * M * H * 4 + 1024 > ws_size) splits >>= 1;
  float* Cp = (float*)carve((size_t)splits * M * H * 4);               // 32.8 MB @4

  // fused dtype prep: convert x + transpose all weights (1 launch instead of 5)
  prep<<<2048 + 3136 + 256 + 32 + 96, 256, 0, stream>>>(
      x, xb, (long)M * D / 4, W6, W6T, W7, W7T, Wcls, Wbox, WcbT);

  // f6 = relu(x @ W6 + b6): split-K MFMA GEMM + reduce
  gemm_bf16<0><<<16 * 8 * splits, 256, 0, stream>>>(xb, W6T, M, H, D, 16, 8, splits,
                                                    Cp, nullptr, nullptr, nullptr, 0,
                                                    (size_t)M * H);
  reduce_bias_act<<<2048, 256, 0, stream>>>(Cp, splits, (size_t)M * H, b6, out, f6b, M);

  // f7 = relu(f6 @ W7 + b7)
  gemm_bf16<1><<<16 * 8, 256, 0, stream>>>(f6b, W7T, M, H, H, 16, 8, 1,
                                           nullptr, f7b, b7, nullptr, 0, 0);

  // [logits | reg] = f7 @ [Wcls | Wbox] + [bcls | bbox_b]   (N=405 -> 4 tiles)
  gemm_bf16<2><<<16 * 4, 256, 0, stream>>>(f7b, WcbT, M, 405, H, 16, 4, 1,
                                           cbv, nullptr, bcls, bboxb, 405, 0);

  // softmax + decode + mask -> out cols [0,400)
  head_epilogue<<<(M + 3) / 4, 256, 0, stream>>>(cbv, boxes, out, M);
}